// Round 5
// baseline (37.673 us; speedup 1.0000x reference)
//
#include <hip/hip_runtime.h>

#define BB 4096
#define NN 64
#define DD 128
#define G  2

typedef float fx4 __attribute__((ext_vector_type(4)));

// Fused, G=2 rows of b per block (2048 blocks -> ~8 blocks/CU of work vs ~6
// resident: dispatcher refill staggers block phases so HBM stays fed).
// Phase 1 (per row): tile in registers, logits via half-wave shfl reduce,
//   redundant per-wave softmax, weighted sum in registers.
//   u = [65*stu ; 64*conc + v] built in LDS.
// Phase 2 (per block): y[2 rows] = mask_s/2 * (u @ Ws + 65*bs), Ws from L2.
__global__ __launch_bounds__(256) void kFused(
    const float* __restrict__ stu,
    const float* __restrict__ conc,
    const float* __restrict__ nbr,
    const float* __restrict__ Ws,
    const float* __restrict__ bs,
    const float* __restrict__ Ww,
    float* __restrict__ y)
{
    const int t    = threadIdx.x;
    const int lane = t & 63;        // lane within wave
    const int cg   = t & 31;        // float4 column group (cols cg*4..+3)
    const int g8   = t >> 5;        // half-wave group 0..7
    const int wv   = t >> 6;        // wave 0..3
    const int b0   = blockIdx.x * G;

    __shared__ float logits[NN];
    __shared__ __align__(16) float part[4 * DD];        // 2 KB
    __shared__ __align__(16) float u[G][2 * DD];        // 2 KB
    __shared__ __align__(16) float scratch[8 * G * DD]; // 8 KB (phase 2)

    const float4 wb = reinterpret_cast<const float4*>(Ww + DD)[cg];  // Ww_b
    float msk0 = 0.f, msk1 = 0.f;

    const fx4* nb4 = reinterpret_cast<const fx4*>(nbr);

#pragma unroll
    for (int g = 0; g < G; ++g) {
        const int b = b0 + g;

        // ---- neighbor tile -> registers (rows g8+8i, cols cg*4..+3), nt ----
        fx4 val[8];
#pragma unroll
        for (int i = 0; i < 8; ++i)
            val[i] = __builtin_nontemporal_load(&nb4[(size_t)b * 2048 + t + 256 * i]);

        // ---- per-wave redundant row sums (masks) + u staging source ----
        float cv0 = conc[(size_t)b * DD + lane];
        float cv1 = conc[(size_t)b * DD + 64 + lane];
        float sv0 = stu [(size_t)b * DD + lane];
        float sv1 = stu [(size_t)b * DD + 64 + lane];
        float cs = cv0 + cv1, ss = sv0 + sv1;
#pragma unroll
        for (int o = 1; o < 64; o <<= 1) {
            cs += __shfl_xor(cs, o);
            ss += __shfl_xor(ss, o);
        }
        const float mg = (ss != 0.0f) ? 0.5f : 0.0f;
        if (g == 0) msk0 = mg; else msk1 = mg;

        if (t < 64) {                       // wave 0 stages u
            u[g][t]           = 65.0f * sv0;
            u[g][64 + t]      = 65.0f * sv1;
            u[g][DD + t]      = 64.0f * cv0;
            u[g][DD + 64 + t] = 64.0f * cv1;
        }

        // ---- logits: row dot with Ww_b, half-wave reduce ----
#pragma unroll
        for (int i = 0; i < 8; ++i) {
            float x = val[i].x * wb.x + val[i].y * wb.y
                    + val[i].z * wb.z + val[i].w * wb.w;
            x += __shfl_xor(x, 1);
            x += __shfl_xor(x, 2);
            x += __shfl_xor(x, 4);
            x += __shfl_xor(x, 8);
            x += __shfl_xor(x, 16);
            if (cg == 0) logits[g8 + 8 * i] = x;
        }
        __syncthreads();                    // barrier 1: logits visible

        // ---- softmax, redundantly in every wave ----
        float l = logits[lane];
        float m = l;
        m = fmaxf(m, __shfl_xor(m, 1));
        m = fmaxf(m, __shfl_xor(m, 2));
        m = fmaxf(m, __shfl_xor(m, 4));
        m = fmaxf(m, __shfl_xor(m, 8));
        m = fmaxf(m, __shfl_xor(m, 16));
        m = fmaxf(m, __shfl_xor(m, 32));
        float e = __expf(l - m);
        float sden = e;
        sden += __shfl_xor(sden, 1);
        sden += __shfl_xor(sden, 2);
        sden += __shfl_xor(sden, 4);
        sden += __shfl_xor(sden, 8);
        sden += __shfl_xor(sden, 16);
        sden += __shfl_xor(sden, 32);
        const float wlane = (cs != 0.0f) ? (e / sden) : (1.0f / 64.0f);

        // ---- weighted sum in registers ----
        float4 a = {0.f, 0.f, 0.f, 0.f};
#pragma unroll
        for (int i = 0; i < 8; ++i) {
            float w = __shfl(wlane, g8 + 8 * i);
            a.x += w * val[i].x; a.y += w * val[i].y;
            a.z += w * val[i].z; a.w += w * val[i].w;
        }
        a.x += __shfl_xor(a.x, 32);
        a.y += __shfl_xor(a.y, 32);
        a.z += __shfl_xor(a.z, 32);
        a.w += __shfl_xor(a.w, 32);
        if (lane < 32)
            reinterpret_cast<float4*>(part)[wv * 32 + cg] = a;
        __syncthreads();                    // barrier 2: partials visible

        if (t < DD)
            u[g][DD + t] += part[t] + part[DD + t] + part[2 * DD + t] + part[3 * DD + t];
        // next g's logits/part writes are fenced by its own barrier 1.
    }
    __syncthreads();                        // u complete

    // ---- phase 2: y[b0+r] = msk[r] * (u[r] @ Ws + 65*bs) ----
    float4 acc0 = {0,0,0,0}, acc1 = {0,0,0,0};
    const float4* Ws4 = reinterpret_cast<const float4*>(Ws);   // 256 x 32 float4
#pragma unroll 4
    for (int j = 0; j < 32; ++j) {
        const int k = g8 * 32 + j;          // k-group per half-wave
        float4 wq = Ws4[k * 32 + cg];       // coalesced, L2-resident
        float u0 = u[0][k], u1 = u[1][k];
        acc0.x += u0 * wq.x; acc0.y += u0 * wq.y; acc0.z += u0 * wq.z; acc0.w += u0 * wq.w;
        acc1.x += u1 * wq.x; acc1.y += u1 * wq.y; acc1.z += u1 * wq.z; acc1.w += u1 * wq.w;
    }
    {
        float4* pr = reinterpret_cast<float4*>(scratch);       // pr[g8][r][32]
        pr[(g8 * G + 0) * 32 + cg] = acc0;
        pr[(g8 * G + 1) * 32 + cg] = acc1;
    }
    __syncthreads();
    {
        const int r = t >> 7;               // 0/1
        const int c = t & 127;
        float s = 0.0f;
#pragma unroll
        for (int k2 = 0; k2 < 8; ++k2)
            s += scratch[(k2 * G + r) * DD + c];
        const float mr = r ? msk1 : msk0;
        y[(size_t)(b0 + r) * DD + c] = (s + 65.0f * bs[c]) * mr;
    }
}

extern "C" void kernel_launch(void* const* d_in, const int* in_sizes, int n_in,
                              void* d_out, int out_size, void* d_ws, size_t ws_size,
                              hipStream_t stream) {
    const float* stu  = (const float*)d_in[0];
    const float* conc = (const float*)d_in[1];
    const float* nbr  = (const float*)d_in[2];
    const float* Ws   = (const float*)d_in[3];
    const float* bs   = (const float*)d_in[4];
    const float* Ww   = (const float*)d_in[5];
    float* y = (float*)d_out;

    kFused<<<BB / G, 256, 0, stream>>>(stu, conc, nbr, Ws, bs, Ww, y);
}

// Round 6
// 30.895 us; speedup vs baseline: 1.2194x; 1.2194x over previous
//
#include <hip/hip_runtime.h>

#define BB 4096
#define NN 64
#define DD 128
#define G  4
#define P2S 36   // part2 row stride in floats: 144B rows (16B-aligned), low-conflict

// Fused, G=4 rows of b per block (1024 blocks, 256 threads) — R2 structure,
// with the 40-shuffle logit reduction replaced by LDS partials (H1 test).
// Phase 1 per row: tile in registers; logits = nbr_row . Ww_b via per-thread
//   dot4 partials -> LDS -> per-wave b128 reduce; wave0 softmax; register
//   weighted sum. u = [65*stu ; 64*conc + v] in LDS.
// Phase 2: y = mask_s/2 * (u @ Ws + 65*bs), Ws from L2.
__global__ __launch_bounds__(256) void kFused(
    const float* __restrict__ stu,
    const float* __restrict__ conc,
    const float* __restrict__ nbr,
    const float* __restrict__ Ws,
    const float* __restrict__ bs,
    const float* __restrict__ Ww,
    float* __restrict__ y)
{
    const int t    = threadIdx.x;
    const int lane = t & 63;
    const int cg   = t & 31;        // float4 column group (cols cg*4..+3)
    const int g8   = t >> 5;        // half-wave group 0..7 (rows g8+8i)
    const int wv   = t >> 6;        // wave 0..3
    const int b0   = blockIdx.x * G;

    __shared__ __align__(16) float part2[NN * P2S];     // 9.2 KB logit partials
    __shared__ float logits[NN];
    __shared__ float wsm[NN];
    __shared__ float sred[2][2];                        // [wave][0]=conc,[1]=stu
    __shared__ float maskh[G];
    __shared__ __align__(16) float u[G][2 * DD];        // 4 KB
    __shared__ __align__(16) float scratch[8 * G * DD]; // 16 KB

    const float4 wb = reinterpret_cast<const float4*>(Ww + DD)[cg];  // Ww_b

    const float4* nb4 = reinterpret_cast<const float4*>(nbr);

    for (int g = 0; g < G; ++g) {
        const int b = b0 + g;

        // ---- sec1: tile -> registers; dot4 partials -> part2 ----
        float4 val[8];
#pragma unroll
        for (int i = 0; i < 8; ++i) val[i] = nb4[(size_t)b * 2048 + t + 256 * i];
#pragma unroll
        for (int i = 0; i < 8; ++i) {
            const int row = g8 + 8 * i;
            part2[row * P2S + cg] =
                val[i].x * wb.x + val[i].y * wb.y + val[i].z * wb.z + val[i].w * wb.w;
        }

        // masks + u staging (waves 0,1)
        if (t < DD) {
            float cs = conc[(size_t)b * DD + t];
            float ss = stu [(size_t)b * DD + t];
            u[g][t]      = 65.0f * ss;
            u[g][DD + t] = 64.0f * cs;          // + v added later by same thread
            float c2 = cs, s2 = ss;
#pragma unroll
            for (int o = 1; o < 64; o <<= 1) {
                c2 += __shfl_xor(c2, o);
                s2 += __shfl_xor(s2, o);
            }
            if ((t & 63) == 0) { sred[t >> 6][0] = c2; sred[t >> 6][1] = s2; }
        }
        __syncthreads();                        // B1: part2 + sred ready

        // ---- sec2: per-wave reduce of 16 rows (2 b128 + 2 shfl) ----
        {
            const int rr = wv * 16 + (lane & 15);
            const int c4 = lane >> 4;           // 0..3
            const float4 pa = *reinterpret_cast<const float4*>(&part2[rr * P2S + c4 * 4]);
            const float4 pb = *reinterpret_cast<const float4*>(&part2[rr * P2S + 16 + c4 * 4]);
            float x = pa.x + pa.y + pa.z + pa.w + pb.x + pb.y + pb.z + pb.w;
            x += __shfl_xor(x, 16);
            x += __shfl_xor(x, 32);
            if (c4 == 0 && (lane & 48) == 0) logits[rr] = x;
        }
        __syncthreads();                        // B2: logits ready

        // ---- sec3: softmax (wave 0 only) ----
        if (t < NN) {
            float csum = sred[0][0] + sred[1][0];
            float l = logits[t];
            float m = l;
            m = fmaxf(m, __shfl_xor(m, 1));
            m = fmaxf(m, __shfl_xor(m, 2));
            m = fmaxf(m, __shfl_xor(m, 4));
            m = fmaxf(m, __shfl_xor(m, 8));
            m = fmaxf(m, __shfl_xor(m, 16));
            m = fmaxf(m, __shfl_xor(m, 32));
            float e = __expf(l - m);
            float s = e;
            s += __shfl_xor(s, 1);
            s += __shfl_xor(s, 2);
            s += __shfl_xor(s, 4);
            s += __shfl_xor(s, 8);
            s += __shfl_xor(s, 16);
            s += __shfl_xor(s, 32);
            wsm[t] = (csum != 0.0f) ? (e / s) : (1.0f / 64.0f);
        }
        if (t == 0) maskh[g] = (sred[0][1] + sred[1][1] != 0.0f) ? 0.5f : 0.0f;
        __syncthreads();                        // B3: wsm ready

        // ---- sec4: weighted sum in registers ----
        float4 a = {0.f, 0.f, 0.f, 0.f};
#pragma unroll
        for (int i = 0; i < 8; ++i) {
            float w = wsm[g8 + 8 * i];          // LDS broadcast within half-wave
            a.x += w * val[i].x; a.y += w * val[i].y;
            a.z += w * val[i].z; a.w += w * val[i].w;
        }
        reinterpret_cast<float4*>(scratch)[g8 * 32 + cg] = a;   // part[g8][cg]
        __syncthreads();                        // B4: partials ready

        // ---- sec5: fold 8 groups into u ----
        if (t < DD) {
            float s = 0.0f;
#pragma unroll
            for (int k = 0; k < 8; ++k) s += scratch[k * DD + t];
            u[g][DD + t] += s;
        }
    }
    __syncthreads();                            // u complete

    // ---- phase 2: y[b0+r] = maskh[r] * (u[r] @ Ws + 65*bs) ----
    float4 acc0 = {0,0,0,0}, acc1 = {0,0,0,0}, acc2 = {0,0,0,0}, acc3 = {0,0,0,0};
    const float4* Ws4 = reinterpret_cast<const float4*>(Ws);    // 256 x 32 float4
#pragma unroll 4
    for (int j = 0; j < 32; ++j) {
        const int k = g8 * 32 + j;
        float4 wq = Ws4[k * 32 + cg];           // coalesced, L2-resident
        float u0 = u[0][k], u1 = u[1][k], u2 = u[2][k], u3 = u[3][k];
        acc0.x += u0 * wq.x; acc0.y += u0 * wq.y; acc0.z += u0 * wq.z; acc0.w += u0 * wq.w;
        acc1.x += u1 * wq.x; acc1.y += u1 * wq.y; acc1.z += u1 * wq.z; acc1.w += u1 * wq.w;
        acc2.x += u2 * wq.x; acc2.y += u2 * wq.y; acc2.z += u2 * wq.z; acc2.w += u2 * wq.w;
        acc3.x += u3 * wq.x; acc3.y += u3 * wq.y; acc3.z += u3 * wq.z; acc3.w += u3 * wq.w;
    }
    {
        float4* pr = reinterpret_cast<float4*>(scratch);        // pr[g8][r][32]
        pr[(g8 * G + 0) * 32 + cg] = acc0;
        pr[(g8 * G + 1) * 32 + cg] = acc1;
        pr[(g8 * G + 2) * 32 + cg] = acc2;
        pr[(g8 * G + 3) * 32 + cg] = acc3;
    }
    __syncthreads();
#pragma unroll
    for (int i = 0; i < 2; ++i) {
        const int idx = t + 256 * i;            // 0..511
        const int r = idx >> 7;
        const int c = idx & 127;
        float s = 0.0f;
#pragma unroll
        for (int k2 = 0; k2 < 8; ++k2) s += scratch[(k2 * G + r) * DD + c];
        y[(size_t)(b0 + r) * DD + c] = (s + 65.0f * bs[c]) * maskh[r];
    }
}

extern "C" void kernel_launch(void* const* d_in, const int* in_sizes, int n_in,
                              void* d_out, int out_size, void* d_ws, size_t ws_size,
                              hipStream_t stream) {
    const float* stu  = (const float*)d_in[0];
    const float* conc = (const float*)d_in[1];
    const float* nbr  = (const float*)d_in[2];
    const float* Ws   = (const float*)d_in[3];
    const float* bs   = (const float*)d_in[4];
    const float* Ww   = (const float*)d_in[5];
    float* y = (float*)d_out;

    kFused<<<BB / G, 256, 0, stream>>>(stu, conc, nbr, Ws, bs, Ww, y);
}

// Round 7
// 29.948 us; speedup vs baseline: 1.2579x; 1.0316x over previous
//
#include <hip/hip_runtime.h>

#define BB 4096
#define NN 64
#define DD 128
#define G  4
#define P2S 36   // part2 row stride (floats): 144B rows, 16B-aligned

// Fused, G=4 rows per block (1024 blocks, 256 threads).
// Upfront: masks + u = [65*stu ; 64*conc] staged, one b-row per wave.
// Per g (2 barriers): tile in regs (double-buffered), dot4 partials -> LDS;
//   B1; wave0: row-reduce (8x b128) + softmax -> wsm; B2; all waves: weighted
//   sum from regs -> per-g scratch. Fold + phase-2 GEMM (u @ Ws) at the end.
__global__ __launch_bounds__(256) void kFused(
    const float* __restrict__ stu,
    const float* __restrict__ conc,
    const float* __restrict__ nbr,
    const float* __restrict__ Ws,
    const float* __restrict__ bs,
    const float* __restrict__ Ww,
    float* __restrict__ y)
{
    const int t    = threadIdx.x;
    const int lane = t & 63;
    const int cg   = t & 31;        // float4 column group (cols cg*4..+3)
    const int g8   = t >> 5;        // half-wave group 0..7 (rows g8+8i)
    const int wv   = t >> 6;        // wave 0..3
    const int b0   = blockIdx.x * G;

    __shared__ __align__(16) float part2[NN * P2S];      // 9 KB logit partials
    __shared__ float wsm[NN];
    __shared__ float csum[G];
    __shared__ float maskh[G];
    __shared__ __align__(16) float u[G][2 * DD];         // 4 KB
    __shared__ __align__(16) float scratch[G * 8 * DD];  // 16 KB

    const float4 wb = reinterpret_cast<const float4*>(Ww + DD)[cg];  // Ww_b
    const float4* nb4 = reinterpret_cast<const float4*>(nbr);

    // ---- upfront: masks + u staging, one b-row per wave ----
    {
        const int b = b0 + wv;
        float cv0 = conc[(size_t)b * DD + lane];
        float cv1 = conc[(size_t)b * DD + 64 + lane];
        float sv0 = stu [(size_t)b * DD + lane];
        float sv1 = stu [(size_t)b * DD + 64 + lane];
        u[wv][lane]           = 65.0f * sv0;
        u[wv][64 + lane]      = 65.0f * sv1;
        u[wv][DD + lane]      = 64.0f * cv0;
        u[wv][DD + 64 + lane] = 64.0f * cv1;
        float cs = cv0 + cv1, ss = sv0 + sv1;
#pragma unroll
        for (int o = 1; o < 64; o <<= 1) {
            cs += __shfl_xor(cs, o);
            ss += __shfl_xor(ss, o);
        }
        if (lane == 0) {
            csum[wv]  = cs;
            maskh[wv] = (ss != 0.0f) ? 0.5f : 0.0f;
        }
    }

    // ---- pre-load tile for g=0 ----
    float4 val[8], valn[8];
#pragma unroll
    for (int i = 0; i < 8; ++i)
        val[i] = nb4[(size_t)b0 * 2048 + t + 256 * i];

    for (int g = 0; g < G; ++g) {
        // ---- dot4 partials -> part2 (2-way LDS writes, free) ----
#pragma unroll
        for (int i = 0; i < 8; ++i) {
            const int row = g8 + 8 * i;
            part2[row * P2S + cg] =
                val[i].x * wb.x + val[i].y * wb.y + val[i].z * wb.z + val[i].w * wb.w;
        }
        // ---- prefetch g+1 tile (hides HBM latency under reduce/softmax) ----
        if (g < G - 1) {
#pragma unroll
            for (int i = 0; i < 8; ++i)
                valn[i] = nb4[(size_t)(b0 + g + 1) * 2048 + t + 256 * i];
        }
        __syncthreads();                    // B1: part2 ready (+ upfront csum)

        // ---- wave0: reduce 64 rows + softmax ----
        if (t < NN) {
            float s = 0.0f;
#pragma unroll
            for (int j = 0; j < 8; ++j) {
                const float4 p = *reinterpret_cast<const float4*>(&part2[t * P2S + j * 4]);
                s += p.x + p.y + p.z + p.w;
            }
            float m = s;
            m = fmaxf(m, __shfl_xor(m, 1));
            m = fmaxf(m, __shfl_xor(m, 2));
            m = fmaxf(m, __shfl_xor(m, 4));
            m = fmaxf(m, __shfl_xor(m, 8));
            m = fmaxf(m, __shfl_xor(m, 16));
            m = fmaxf(m, __shfl_xor(m, 32));
            float e = __expf(s - m);
            float den = e;
            den += __shfl_xor(den, 1);
            den += __shfl_xor(den, 2);
            den += __shfl_xor(den, 4);
            den += __shfl_xor(den, 8);
            den += __shfl_xor(den, 16);
            den += __shfl_xor(den, 32);
            wsm[t] = (csum[g] != 0.0f) ? (e / den) : (1.0f / 64.0f);
        }
        __syncthreads();                    // B2: wsm ready

        // ---- weighted sum in registers -> per-g scratch ----
        float4 a = {0.f, 0.f, 0.f, 0.f};
#pragma unroll
        for (int i = 0; i < 8; ++i) {
            const float w = wsm[g8 + 8 * i];    // LDS broadcast
            a.x += w * val[i].x; a.y += w * val[i].y;
            a.z += w * val[i].z; a.w += w * val[i].w;
        }
        reinterpret_cast<float4*>(scratch + g * 8 * DD)[g8 * 32 + cg] = a;

        if (g < G - 1) {
#pragma unroll
            for (int i = 0; i < 8; ++i) val[i] = valn[i];
        }
    }
    __syncthreads();                        // scratch + u staging visible

    // ---- fold weighted-sum partials into u ----
#pragma unroll
    for (int it = 0; it < 2; ++it) {
        const int idx = t + 256 * it;       // 0..511
        const int gg  = idx >> 7;
        const int c   = idx & 127;
        float s = 0.0f;
#pragma unroll
        for (int k = 0; k < 8; ++k) s += scratch[gg * 8 * DD + k * DD + c];
        u[gg][DD + c] += s;
    }
    __syncthreads();                        // u complete

    // ---- phase 2: y[b0+r] = maskh[r] * (u[r] @ Ws + 65*bs) ----
    float4 acc0 = {0,0,0,0}, acc1 = {0,0,0,0}, acc2 = {0,0,0,0}, acc3 = {0,0,0,0};
    const float4* Ws4 = reinterpret_cast<const float4*>(Ws);    // 256 x 32 float4
#pragma unroll 4
    for (int j = 0; j < 32; ++j) {
        const int k = g8 * 32 + j;
        float4 wq = Ws4[k * 32 + cg];       // coalesced, L2-resident
        float u0 = u[0][k], u1 = u[1][k], u2 = u[2][k], u3 = u[3][k];
        acc0.x += u0 * wq.x; acc0.y += u0 * wq.y; acc0.z += u0 * wq.z; acc0.w += u0 * wq.w;
        acc1.x += u1 * wq.x; acc1.y += u1 * wq.y; acc1.z += u1 * wq.z; acc1.w += u1 * wq.w;
        acc2.x += u2 * wq.x; acc2.y += u2 * wq.y; acc2.z += u2 * wq.z; acc2.w += u2 * wq.w;
        acc3.x += u3 * wq.x; acc3.y += u3 * wq.y; acc3.z += u3 * wq.z; acc3.w += u3 * wq.w;
    }
    {
        float4* pr = reinterpret_cast<float4*>(scratch);        // pr[g8][r][32]
        pr[(g8 * G + 0) * 32 + cg] = acc0;
        pr[(g8 * G + 1) * 32 + cg] = acc1;
        pr[(g8 * G + 2) * 32 + cg] = acc2;
        pr[(g8 * G + 3) * 32 + cg] = acc3;
    }
    __syncthreads();
#pragma unroll
    for (int i = 0; i < 2; ++i) {
        const int idx = t + 256 * i;        // 0..511
        const int r = idx >> 7;
        const int c = idx & 127;
        float s = 0.0f;
#pragma unroll
        for (int k2 = 0; k2 < 8; ++k2) s += scratch[(k2 * G + r) * DD + c];
        y[(size_t)(b0 + r) * DD + c] = (s + 65.0f * bs[c]) * maskh[r];
    }
}

extern "C" void kernel_launch(void* const* d_in, const int* in_sizes, int n_in,
                              void* d_out, int out_size, void* d_ws, size_t ws_size,
                              hipStream_t stream) {
    const float* stu  = (const float*)d_in[0];
    const float* conc = (const float*)d_in[1];
    const float* nbr  = (const float*)d_in[2];
    const float* Ws   = (const float*)d_in[3];
    const float* bs   = (const float*)d_in[4];
    const float* Ww   = (const float*)d_in[5];
    float* y = (float*)d_out;

    kFused<<<BB / G, 256, 0, stream>>>(stu, conc, nbr, Ws, bs, Ww, y);
}